// Round 5
// baseline (639.807 us; speedup 1.0000x reference)
//
#include <hip/hip_runtime.h>
#include <hip/hip_bf16.h>

// LengthRegulator on MI355X — R5: small kernels reverted to R3 (measured-good);
// conv_mfma gains T14 async-STAGE split (load chunk+1 during MFMA of chunk).
//   d_out: [0,B*T) durations (as float), [B*T, ...) aligned [B,H,MAXL].
//   h_raw (fp32 [b][t][384]) aliases the aligned region (gather runs last).

#define BB 32
#define HHD 384
#define TTOT 1024
#define MAXL 4096

typedef _Float16 half8 __attribute__((ext_vector_type(8)));
typedef float floatx4 __attribute__((ext_vector_type(4)));

// ---------------------------------------------------------------------------
// prep_w: W[h][hi][k] fp32 -> Wq[s] f16, layout e = ((c*3+k)*384 + h)*32 + d,
// where c = hi/32, d = hi%32. Split: hi = f16(w), lo = f16((w-hi)*2048).
__global__ void prep_w_kernel(const float* __restrict__ W1,
                              const float* __restrict__ W2,
                              _Float16* __restrict__ q1h, _Float16* __restrict__ q1l,
                              _Float16* __restrict__ q2h, _Float16* __restrict__ q2l) {
    const int e = blockIdx.x * 256 + threadIdx.x;     // < 442368
    const float* W = blockIdx.y ? W2 : W1;
    _Float16* oh = blockIdx.y ? q2h : q1h;
    _Float16* ol = blockIdx.y ? q2l : q1l;
    const int d  = e & 31;
    const int m  = (e >> 5) % 384;
    const int ck = e / (32 * 384);
    const int c  = ck / 3, k = ck - 3 * c;
    const float w = W[(size_t)m * 1152 + (size_t)(32 * c + d) * 3 + k];
    const _Float16 hi = (_Float16)w;
    oh[e] = hi;
    ol[e] = (_Float16)((w - (float)hi) * 2048.0f);
}

// ---------------------------------------------------------------------------
// prep_x: x[b][h][t] fp32 -> Xt1/Xt2 f16 [b][t][384] (transposed + split). [R3]
__global__ void prep_x_kernel(const float* __restrict__ X,
                              _Float16* __restrict__ o1,
                              _Float16* __restrict__ o2) {
    __shared__ float Ls[64][65];
    const int h0 = blockIdx.x * 64;
    const int t0 = blockIdx.y * 64;
    const int b  = blockIdx.z;
    const int tid = threadIdx.x;
    const int tl = tid & 63, hq = tid >> 6;
    const float* Xb = X + (size_t)b * HHD * TTOT;
#pragma unroll
    for (int i = 0; i < 16; ++i) {
        const int h = i * 4 + hq;
        Ls[tl][h] = Xb[(size_t)(h0 + h) * TTOT + t0 + tl];
    }
    __syncthreads();
#pragma unroll
    for (int i = 0; i < 16; ++i) {
        const int t = i * 4 + hq;
        const float v = Ls[t][tl];
        const _Float16 a = (_Float16)v;
        const size_t o = ((size_t)b * TTOT + t0 + t) * HHD + h0 + tl;
        o1[o] = a;
        o2[o] = (_Float16)((v - (float)a) * 2048.0f);
    }
}

// ---------------------------------------------------------------------------
// conv_mfma: C[96 m][128 t] per block. K = 12 chunks x (3 k-steps of 32).
// T14 async-STAGE: regs hold chunk ch+1's data while MFMA consumes chunk ch.
// Loop: barrier -> ds_write(regs) -> barrier -> issue loads ch+1 -> MFMA ch.
// 4 waves, wave tile 48x64. LDS 66,880 B -> 2 blocks/CU.
__launch_bounds__(256, 2)
__global__ void conv_mfma_kernel(const _Float16* __restrict__ Bh,  // [b][t][384]
                                 const _Float16* __restrict__ Bl,
                                 const _Float16* __restrict__ Ah,  // Wq hi
                                 const _Float16* __restrict__ Al,  // Wq lo
                                 const float* __restrict__ bias,
                                 float* __restrict__ Out) {        // h_raw [b][t][384]
    __shared__ __align__(16) _Float16 sm[33440];  // W: [2][3][96][40] @0, X: [2][130][40] @23040
    const int tid  = threadIdx.x;
    const int lane = tid & 63, wid = tid >> 6;
    const int wm = wid >> 1, wn = wid & 1;
    const int l15 = lane & 15, g4 = lane >> 4;
    const int h0 = blockIdx.x * 96;
    const int t0 = blockIdx.y * 128;
    const int b  = blockIdx.z;

    floatx4 ahh[3][4], axx[3][4];
#pragma unroll
    for (int mt = 0; mt < 3; ++mt)
#pragma unroll
        for (int nt = 0; nt < 4; ++nt) {
            ahh[mt][nt] = (floatx4){0.f, 0.f, 0.f, 0.f};
            axx[mt][nt] = (floatx4){0.f, 0.f, 0.f, 0.f};
        }

    const size_t xbase = (size_t)b * TTOT * HHD;

    // Thread-constant W-staging decomposition and LDS destinations.
    int wdst[9];
    const _Float16* wsrc0[9];   // ch-invariant part; per-chunk adds ch*3*384*32
#pragma unroll
    for (int it = 0; it < 9; ++it) {
        const int e  = tid + it * 256;
        const int s  = e / 1152;
        const int r1 = e - s * 1152;
        const int k  = r1 / 384;
        const int q  = r1 - k * 384;
        const int m  = q >> 2, c8 = (q & 3) << 3;
        wsrc0[it] = (s ? Al : Ah) + ((size_t)(k * 384 + h0 + m) << 5) + c8;
        wdst[it]  = ((s * 3 + k) * 96 + m) * 40 + c8;
    }
    // Thread-constant X-staging decomposition.
    int xdst[5], xgt[5];
    const _Float16* xsrc0[5];   // ch-invariant; per-chunk adds ch*32
    bool xact[5];
#pragma unroll
    for (int it = 0; it < 5; ++it) {
        const int e = tid + it * 256;
        xact[it] = (e < 1040);
        const int s  = e / 520;
        const int r1 = e - s * 520;
        const int j  = r1 >> 2, q = r1 & 3;
        const int gt = t0 - 1 + j;
        xgt[it]  = gt;
        xsrc0[it] = (s ? Bl : Bh) + xbase + (size_t)max(gt, 0) * HHD + (q << 3);
        xdst[it]  = 23040 + (s * 130 + j) * 40 + (q << 3);
    }

    uint4 wreg[9], xreg[5];
    // Prologue: load chunk 0.
#pragma unroll
    for (int it = 0; it < 9; ++it) wreg[it] = *(const uint4*)(wsrc0[it]);
#pragma unroll
    for (int it = 0; it < 5; ++it) {
        uint4 v = make_uint4(0u, 0u, 0u, 0u);
        if (xact[it] && xgt[it] >= 0 && xgt[it] < TTOT)
            v = *(const uint4*)(xsrc0[it]);
        xreg[it] = v;
    }

    for (int ch = 0; ch < 12; ++ch) {
        __syncthreads();   // previous MFMA phase done reading LDS
#pragma unroll
        for (int it = 0; it < 9; ++it) *(uint4*)&sm[wdst[it]] = wreg[it];
#pragma unroll
        for (int it = 0; it < 5; ++it)
            if (xact[it]) *(uint4*)&sm[xdst[it]] = xreg[it];
        __syncthreads();

        // Issue chunk ch+1 loads; latency hides under this chunk's MFMA.
        if (ch < 11) {
            const size_t woff = (size_t)(ch + 1) * 3 * 384 * 32;
            const int    xoff = (ch + 1) * 32;
#pragma unroll
            for (int it = 0; it < 9; ++it) wreg[it] = *(const uint4*)(wsrc0[it] + woff);
#pragma unroll
            for (int it = 0; it < 5; ++it) {
                uint4 v = make_uint4(0u, 0u, 0u, 0u);
                if (xact[it] && xgt[it] >= 0 && xgt[it] < TTOT)
                    v = *(const uint4*)(xsrc0[it] + xoff);
                xreg[it] = v;
            }
        }

#pragma unroll
        for (int k = 0; k < 3; ++k) {
            half8 ah[3], al[3], bh[4], bl[4];
#pragma unroll
            for (int mt = 0; mt < 3; ++mt) {
                const int m = wm * 48 + mt * 16 + l15;
                ah[mt] = *(const half8*)&sm[((0 + k) * 96 + m) * 40 + g4 * 8];
                al[mt] = *(const half8*)&sm[((3 + k) * 96 + m) * 40 + g4 * 8];
            }
#pragma unroll
            for (int nt = 0; nt < 4; ++nt) {
                const int j = wn * 64 + nt * 16 + l15 + k;
                bh[nt] = *(const half8*)&sm[23040 + (0   + j) * 40 + g4 * 8];
                bl[nt] = *(const half8*)&sm[23040 + (130 + j) * 40 + g4 * 8];
            }
#pragma unroll
            for (int mt = 0; mt < 3; ++mt)
#pragma unroll
                for (int nt = 0; nt < 4; ++nt) {
                    ahh[mt][nt] = __builtin_amdgcn_mfma_f32_16x16x32_f16(
                        ah[mt], bh[nt], ahh[mt][nt], 0, 0, 0);
                    axx[mt][nt] = __builtin_amdgcn_mfma_f32_16x16x32_f16(
                        ah[mt], bl[nt], axx[mt][nt], 0, 0, 0);
                    axx[mt][nt] = __builtin_amdgcn_mfma_f32_16x16x32_f16(
                        al[mt], bh[nt], axx[mt][nt], 0, 0, 0);
                }
        }
    }

    // --- epilogue: recombine, transpose via LDS, coalesced [b][t][h] write ---
    __syncthreads();
    float* Lt = (float*)sm;  // [128][100]
#pragma unroll
    for (int mt = 0; mt < 3; ++mt)
#pragma unroll
        for (int nt = 0; nt < 4; ++nt) {
            const int row = wn * 64 + nt * 16 + l15;     // t within tile
            const int col = wm * 48 + mt * 16 + g4 * 4;  // h within tile
            float4 v;
            v.x = ahh[mt][nt][0] + axx[mt][nt][0] * (1.0f / 2048.0f);
            v.y = ahh[mt][nt][1] + axx[mt][nt][1] * (1.0f / 2048.0f);
            v.z = ahh[mt][nt][2] + axx[mt][nt][2] * (1.0f / 2048.0f);
            v.w = ahh[mt][nt][3] + axx[mt][nt][3] * (1.0f / 2048.0f);
            *(float4*)&Lt[row * 100 + col] = v;
        }
    __syncthreads();
    const size_t obase = ((size_t)b * TTOT + t0) * HHD + h0;
#pragma unroll
    for (int i = 0; i < 12; ++i) {
        const int e = tid + i * 256;
        const int row = e / 24, c4 = (e - row * 24) * 4;
        float4 v = *(const float4*)&Lt[row * 100 + c4];
        const float4 bv = *(const float4*)&bias[h0 + c4];
        v.x += bv.x; v.y += bv.y; v.z += bv.z; v.w += bv.w;
        *(float4*)&Out[obase + (size_t)row * HHD + c4] = v;
    }
}

// ---------------------------------------------------------------------------
// ln_split: LayerNorm(ch) + ReLU on h_raw [row=b*T+t][384], emit f16 splits. [R3]
__global__ void ln_split_kernel(const float* __restrict__ hraw,
                                const float* __restrict__ g,
                                const float* __restrict__ be,
                                _Float16* __restrict__ o1,
                                _Float16* __restrict__ o2) {
    const int row = blockIdx.x * 4 + (threadIdx.x >> 6);
    const int ln  = threadIdx.x & 63;
    const float* src = hraw + (size_t)row * HHD;
    float v[6], s = 0.f, ss = 0.f;
#pragma unroll
    for (int j = 0; j < 6; ++j) { v[j] = src[ln + 64 * j]; s += v[j]; ss += v[j] * v[j]; }
#pragma unroll
    for (int m = 32; m >= 1; m >>= 1) { s += __shfl_xor(s, m, 64); ss += __shfl_xor(ss, m, 64); }
    const float mean = s * (1.f / HHD);
    const float var  = ss * (1.f / HHD) - mean * mean;
    const float inv  = rsqrtf(var + 1e-5f);
#pragma unroll
    for (int j = 0; j < 6; ++j) {
        const int h = ln + 64 * j;
        float y = (v[j] - mean) * inv * g[h] + be[h];
        y = fmaxf(y, 0.f);
        const _Float16 a = (_Float16)y;
        const size_t o = (size_t)row * HHD + h;
        o1[o] = a;
        o2[o] = (_Float16)((y - (float)a) * 2048.0f);
    }
}

// ---------------------------------------------------------------------------
// ln_proj: LayerNorm + ReLU + dot(Wl) + bl + ReLU -> z[row]. [R3]
__global__ void ln_proj_kernel(const float* __restrict__ hraw,
                               const float* __restrict__ g,
                               const float* __restrict__ be,
                               const float* __restrict__ Wl,
                               const float* __restrict__ blp,
                               float* __restrict__ zb) {
    const int row = blockIdx.x * 4 + (threadIdx.x >> 6);
    const int ln  = threadIdx.x & 63;
    const float* src = hraw + (size_t)row * HHD;
    float v[6], s = 0.f, ss = 0.f;
#pragma unroll
    for (int j = 0; j < 6; ++j) { v[j] = src[ln + 64 * j]; s += v[j]; ss += v[j] * v[j]; }
#pragma unroll
    for (int m = 32; m >= 1; m >>= 1) { s += __shfl_xor(s, m, 64); ss += __shfl_xor(ss, m, 64); }
    const float mean = s * (1.f / HHD);
    const float inv  = rsqrtf(ss * (1.f / HHD) - mean * mean + 1e-5f);
    float zs = 0.f;
#pragma unroll
    for (int j = 0; j < 6; ++j) {
        const int h = ln + 64 * j;
        float y = (v[j] - mean) * inv * g[h] + be[h];
        zs += fmaxf(y, 0.f) * Wl[h];
    }
#pragma unroll
    for (int m = 32; m >= 1; m >>= 1) zs += __shfl_xor(zs, m, 64);
    if (ln == 0) zb[row] = fmaxf(zs + blp[0], 0.f);
}

// ---------------------------------------------------------------------------
// dur_scan: durations + per-batch inclusive scan. [R3]
__global__ void dur_scan_kernel(const float* __restrict__ z,
                                float* __restrict__ durOut,
                                int* __restrict__ cum) {
    __shared__ int sb[TTOT];
    const int b = blockIdx.x;
    const int t = threadIdx.x;
    const int d = (int)floorf(expf(z[b * TTOT + t]));
    durOut[b * TTOT + t] = (float)d;
    sb[t] = d;
    __syncthreads();
    for (int off = 1; off < TTOT; off <<= 1) {
        const int v = (t >= off) ? sb[t - off] : 0;
        __syncthreads();
        sb[t] += v;
        __syncthreads();
    }
    cum[b * TTOT + t] = sb[t];
}

// ---------------------------------------------------------------------------
// gather: searchsorted + masked gather. [R3]
__global__ void gather_kernel(const float* __restrict__ X,
                              const int* __restrict__ cum,
                              float* __restrict__ aligned) {
    __shared__ int cs[TTOT];
    const int b   = blockIdx.y;
    const int tid = threadIdx.x;
    for (int e = tid; e < TTOT; e += 256) cs[e] = cum[b * TTOT + e];
    __syncthreads();
    const int pos   = blockIdx.x * 256 + tid;
    const int total = cs[TTOT - 1];
    int lo = 0, hi = TTOT;
    while (lo < hi) {
        const int mid = (lo + hi) >> 1;
        if (cs[mid] <= pos) lo = mid + 1; else hi = mid;
    }
    const float vmul = (pos < total) ? 1.f : 0.f;
    const int idx = min(lo, TTOT - 1);
    const float* Xb = X + (size_t)b * HHD * TTOT;
    float* Ab = aligned + (size_t)b * HHD * MAXL;
#pragma unroll 4
    for (int h = 0; h < HHD; ++h)
        Ab[(size_t)h * MAXL + pos] = Xb[(size_t)h * TTOT + idx] * vmul;
}

// ---------------------------------------------------------------------------
extern "C" void kernel_launch(void* const* d_in, const int* in_sizes, int n_in,
                              void* d_out, int out_size, void* d_ws, size_t ws_size,
                              hipStream_t stream) {
    const float* x   = (const float*)d_in[0];
    const float* W1  = (const float*)d_in[1];
    const float* b1  = (const float*)d_in[2];
    const float* g1  = (const float*)d_in[3];
    const float* be1 = (const float*)d_in[4];
    const float* W2  = (const float*)d_in[5];
    const float* b2  = (const float*)d_in[6];
    const float* g2  = (const float*)d_in[7];
    const float* be2 = (const float*)d_in[8];
    const float* Wl  = (const float*)d_in[9];
    const float* bl  = (const float*)d_in[10];

    float* out     = (float*)d_out;
    float* durOut  = out;                        // [B*T]
    float* aligned = out + (size_t)BB * TTOT;    // [B*H*MAXL]
    float* h_raw   = aligned;                    // alias; gather runs last

    char* ws = (char*)d_ws;
    const size_t wqB = (size_t)442368 * sizeof(_Float16);
    const size_t xtB = (size_t)BB * TTOT * HHD * sizeof(_Float16);
    _Float16* Wq1h = (_Float16*)(ws);
    _Float16* Wq1l = (_Float16*)(ws + wqB);
    _Float16* Wq2h = (_Float16*)(ws + 2 * wqB);
    _Float16* Wq2l = (_Float16*)(ws + 3 * wqB);
    _Float16* Xt1  = (_Float16*)(ws + 4 * wqB);          // reused as H1t1
    _Float16* Xt2  = (_Float16*)(ws + 4 * wqB + xtB);    // reused as H1t2
    float*    zb   = (float*)   (ws + 4 * wqB + 2 * xtB);
    int*      cum  = (int*)     (ws + 4 * wqB + 2 * xtB + (size_t)BB * TTOT * 4);

    prep_w_kernel<<<dim3(1728, 2), 256, 0, stream>>>(W1, W2, Wq1h, Wq1l, Wq2h, Wq2l);
    prep_x_kernel<<<dim3(6, 16, 32), 256, 0, stream>>>(x, Xt1, Xt2);
    conv_mfma_kernel<<<dim3(4, 8, 32), 256, 0, stream>>>(Xt1, Xt2, Wq1h, Wq1l, b1, h_raw);
    ln_split_kernel<<<8192, 256, 0, stream>>>(h_raw, g1, be1, Xt1, Xt2);
    conv_mfma_kernel<<<dim3(4, 8, 32), 256, 0, stream>>>(Xt1, Xt2, Wq2h, Wq2l, b2, h_raw);
    ln_proj_kernel<<<8192, 256, 0, stream>>>(h_raw, g2, be2, Wl, bl, zb);
    dur_scan_kernel<<<BB, TTOT, 0, stream>>>(zb, durOut, cum);
    gather_kernel<<<dim3(MAXL / 256, BB), 256, 0, stream>>>(x, cum, aligned);
}

// Round 6
// 484.201 us; speedup vs baseline: 1.3214x; 1.3214x over previous
//
#include <hip/hip_runtime.h>
#include <hip/hip_bf16.h>

// LengthRegulator on MI355X — R6: R3 structure + global_load_lds staging.
// conv: consume-per-chunk schedule (R3), staging via global_load_lds width=16
// (no VGPR round-trip, no ds_write), LDS unpadded (linear dest required),
// 52.2 KB/block -> 3 blocks/CU. Halo zeros applied at consume time.
// Small kernels: R3 forms verbatim (measured-good at 515.8).
//   d_out: [0,B*T) durations (as float), [B*T, ...) aligned [B,H,MAXL].
//   h_raw (fp32 [b][t][384]) aliases the aligned region (gather runs last).

#define BB 32
#define HHD 384
#define TTOT 1024
#define MAXL 4096

typedef _Float16 half8 __attribute__((ext_vector_type(8)));
typedef float floatx4 __attribute__((ext_vector_type(4)));

// ---------------------------------------------------------------------------
// prep_w: W[h][hi][k] fp32 -> Wq[s] f16, layout e = ((c*3+k)*384 + h)*32 + d,
// where c = hi/32, d = hi%32. Split: hi = f16(w), lo = f16((w-hi)*2048).
__global__ void prep_w_kernel(const float* __restrict__ W1,
                              const float* __restrict__ W2,
                              _Float16* __restrict__ q1h, _Float16* __restrict__ q1l,
                              _Float16* __restrict__ q2h, _Float16* __restrict__ q2l) {
    const int e = blockIdx.x * 256 + threadIdx.x;     // < 442368
    const float* W = blockIdx.y ? W2 : W1;
    _Float16* oh = blockIdx.y ? q2h : q1h;
    _Float16* ol = blockIdx.y ? q2l : q1l;
    const int d  = e & 31;
    const int m  = (e >> 5) % 384;
    const int ck = e / (32 * 384);
    const int c  = ck / 3, k = ck - 3 * c;
    const float w = W[(size_t)m * 1152 + (size_t)(32 * c + d) * 3 + k];
    const _Float16 hi = (_Float16)w;
    oh[e] = hi;
    ol[e] = (_Float16)((w - (float)hi) * 2048.0f);
}

// ---------------------------------------------------------------------------
// prep_x: x[b][h][t] fp32 -> Xt1/Xt2 f16 [b][t][384] (transposed + split). [R3]
__global__ void prep_x_kernel(const float* __restrict__ X,
                              _Float16* __restrict__ o1,
                              _Float16* __restrict__ o2) {
    __shared__ float Ls[64][65];
    const int h0 = blockIdx.x * 64;
    const int t0 = blockIdx.y * 64;
    const int b  = blockIdx.z;
    const int tid = threadIdx.x;
    const int tl = tid & 63, hq = tid >> 6;
    const float* Xb = X + (size_t)b * HHD * TTOT;
#pragma unroll
    for (int i = 0; i < 16; ++i) {
        const int h = i * 4 + hq;
        Ls[tl][h] = Xb[(size_t)(h0 + h) * TTOT + t0 + tl];
    }
    __syncthreads();
#pragma unroll
    for (int i = 0; i < 16; ++i) {
        const int t = i * 4 + hq;
        const float v = Ls[t][tl];
        const _Float16 a = (_Float16)v;
        const size_t o = ((size_t)b * TTOT + t0 + t) * HHD + h0 + tl;
        o1[o] = a;
        o2[o] = (_Float16)((v - (float)a) * 2048.0f);
    }
}

// ---------------------------------------------------------------------------
// conv_mfma: C[96 m][128 t] per block. K = 12 chunks x (3 k-steps of 32).
// Staging: global_load_lds width=16, destination linear in lane order.
// LDS: W [2 spl][3 k][96 m][32] @0 (18432 halfs), X [2 spl][130 t][32] @18432
// (8320 halfs). Total 26752 halfs = 52.2 KB -> 3 blocks/CU.
// Halo rows (j=0 at t0==0, j=129 at t0==896) are loaded clamped and zeroed at
// consume time (single reader lane each).
__launch_bounds__(256, 2)
__global__ void conv_mfma_kernel(const _Float16* __restrict__ Bh,  // [b][t][384]
                                 const _Float16* __restrict__ Bl,
                                 const _Float16* __restrict__ Ah,  // Wq hi
                                 const _Float16* __restrict__ Al,  // Wq lo
                                 const float* __restrict__ bias,
                                 float* __restrict__ Out) {        // h_raw [b][t][384]
    __shared__ __align__(16) _Float16 sm[26752];
    const int tid  = threadIdx.x;
    const int lane = tid & 63, wid = tid >> 6;
    const int wm = wid >> 1, wn = wid & 1;
    const int l15 = lane & 15, g4 = lane >> 4;
    const int h0 = blockIdx.x * 96;
    const int t0 = blockIdx.y * 128;
    const int b  = blockIdx.z;
    const int wbid = tid & 192;            // wave-uniform thread base

    const bool haloL = (blockIdx.y == 0) && (wn == 0) && (l15 == 0);
    const bool haloH = (blockIdx.y == 7) && (wn == 1) && (l15 == 15);

    floatx4 ahh[3][4], axx[3][4];
#pragma unroll
    for (int mt = 0; mt < 3; ++mt)
#pragma unroll
        for (int nt = 0; nt < 4; ++nt) {
            ahh[mt][nt] = (floatx4){0.f, 0.f, 0.f, 0.f};
            axx[mt][nt] = (floatx4){0.f, 0.f, 0.f, 0.f};
        }

    const size_t xbase = (size_t)b * TTOT * HHD;

    // ch-invariant per-lane source pointers (chunk adds woff / xoff).
    const _Float16* wsrc[9];
#pragma unroll
    for (int it = 0; it < 9; ++it) {
        const int e  = tid + it * 256;
        const int s  = e / 1152;
        const int r1 = e - s * 1152;
        const int k  = r1 / 384;
        const int q  = r1 - k * 384;
        const int m  = q >> 2, c8 = (q & 3) << 3;
        wsrc[it] = (s ? Al : Ah) + ((size_t)(k * 384 + h0 + m) << 5) + c8;
    }
    const _Float16* xsrc[5];
#pragma unroll
    for (int it = 0; it < 5; ++it) {
        const int e  = tid + it * 256;
        const int s  = e / 520;
        const int r1 = e - s * 520;
        const int j  = r1 >> 2, q = r1 & 3;
        const int gt  = t0 - 1 + j;
        const int gtc = min(max(gt, 0), TTOT - 1);
        xsrc[it] = (s ? Bl : Bh) + xbase + (size_t)gtc * HHD + (q << 3);
    }

    const half8 hz = {0, 0, 0, 0, 0, 0, 0, 0};

    for (int ch = 0; ch < 12; ++ch) {
        __syncthreads();   // previous MFMA phase done reading LDS
        const size_t woff = (size_t)ch * (3 * 384 * 32);
        const int    xoff = ch * 32;
        // W chunk: 2304 lane-slots of 16 B, dest linear at e*16 B.
#pragma unroll
        for (int it = 0; it < 9; ++it) {
            __builtin_amdgcn_global_load_lds(
                (const unsigned int*)(wsrc[it] + woff),
                (unsigned int*)&sm[(size_t)(it * 256 + wbid) * 8], 16, 0, 0);
        }
        // X chunk: 1040 lane-slots, dest linear at 18432*2B + e*16 B.
#pragma unroll
        for (int it = 0; it < 4; ++it) {
            __builtin_amdgcn_global_load_lds(
                (const unsigned int*)(xsrc[it] + xoff),
                (unsigned int*)&sm[18432 + (size_t)(it * 256 + wbid) * 8], 16, 0, 0);
        }
        if (tid < 16) {    // e = 1024..1039 (wave 0, partial EXEC)
            __builtin_amdgcn_global_load_lds(
                (const unsigned int*)(xsrc[4] + xoff),
                (unsigned int*)&sm[18432 + (size_t)(4 * 256) * 8], 16, 0, 0);
        }
        __syncthreads();   // compiler drains vmcnt(0) before barrier

#pragma unroll
        for (int k = 0; k < 3; ++k) {
            half8 ah[3], al[3], bh[4], bl[4];
#pragma unroll
            for (int mt = 0; mt < 3; ++mt) {
                const int m = wm * 48 + mt * 16 + l15;
                ah[mt] = *(const half8*)&sm[((0 + k) * 96 + m) * 32 + g4 * 8];
                al[mt] = *(const half8*)&sm[((3 + k) * 96 + m) * 32 + g4 * 8];
            }
#pragma unroll
            for (int nt = 0; nt < 4; ++nt) {
                const int j = wn * 64 + nt * 16 + l15 + k;
                bh[nt] = *(const half8*)&sm[18432 + (0   + j) * 32 + g4 * 8];
                bl[nt] = *(const half8*)&sm[18432 + (130 + j) * 32 + g4 * 8];
            }
            if (k == 0 && haloL) { bh[0] = hz; bl[0] = hz; }  // row j=0 (t=-1)
            if (k == 2 && haloH) { bh[3] = hz; bl[3] = hz; }  // row j=129 (t=1024)
#pragma unroll
            for (int mt = 0; mt < 3; ++mt)
#pragma unroll
                for (int nt = 0; nt < 4; ++nt) {
                    ahh[mt][nt] = __builtin_amdgcn_mfma_f32_16x16x32_f16(
                        ah[mt], bh[nt], ahh[mt][nt], 0, 0, 0);
                    axx[mt][nt] = __builtin_amdgcn_mfma_f32_16x16x32_f16(
                        ah[mt], bl[nt], axx[mt][nt], 0, 0, 0);
                    axx[mt][nt] = __builtin_amdgcn_mfma_f32_16x16x32_f16(
                        al[mt], bh[nt], axx[mt][nt], 0, 0, 0);
                }
        }
    }

    // --- epilogue: recombine, transpose via LDS, coalesced [b][t][h] write ---
    __syncthreads();
    float* Lt = (float*)sm;  // [128][100] floats = 12800 <= 13376 capacity
#pragma unroll
    for (int mt = 0; mt < 3; ++mt)
#pragma unroll
        for (int nt = 0; nt < 4; ++nt) {
            const int row = wn * 64 + nt * 16 + l15;     // t within tile
            const int col = wm * 48 + mt * 16 + g4 * 4;  // h within tile
            float4 v;
            v.x = ahh[mt][nt][0] + axx[mt][nt][0] * (1.0f / 2048.0f);
            v.y = ahh[mt][nt][1] + axx[mt][nt][1] * (1.0f / 2048.0f);
            v.z = ahh[mt][nt][2] + axx[mt][nt][2] * (1.0f / 2048.0f);
            v.w = ahh[mt][nt][3] + axx[mt][nt][3] * (1.0f / 2048.0f);
            *(float4*)&Lt[row * 100 + col] = v;
        }
    __syncthreads();
    const size_t obase = ((size_t)b * TTOT + t0) * HHD + h0;
#pragma unroll
    for (int i = 0; i < 12; ++i) {
        const int e = tid + i * 256;
        const int row = e / 24, c4 = (e - row * 24) * 4;
        float4 v = *(const float4*)&Lt[row * 100 + c4];
        const float4 bv = *(const float4*)&bias[h0 + c4];
        v.x += bv.x; v.y += bv.y; v.z += bv.z; v.w += bv.w;
        *(float4*)&Out[obase + (size_t)row * HHD + c4] = v;
    }
}

// ---------------------------------------------------------------------------
// ln_split: LayerNorm(ch) + ReLU on h_raw [row=b*T+t][384], emit f16 splits. [R3]
__global__ void ln_split_kernel(const float* __restrict__ hraw,
                                const float* __restrict__ g,
                                const float* __restrict__ be,
                                _Float16* __restrict__ o1,
                                _Float16* __restrict__ o2) {
    const int row = blockIdx.x * 4 + (threadIdx.x >> 6);
    const int ln  = threadIdx.x & 63;
    const float* src = hraw + (size_t)row * HHD;
    float v[6], s = 0.f, ss = 0.f;
#pragma unroll
    for (int j = 0; j < 6; ++j) { v[j] = src[ln + 64 * j]; s += v[j]; ss += v[j] * v[j]; }
#pragma unroll
    for (int m = 32; m >= 1; m >>= 1) { s += __shfl_xor(s, m, 64); ss += __shfl_xor(ss, m, 64); }
    const float mean = s * (1.f / HHD);
    const float var  = ss * (1.f / HHD) - mean * mean;
    const float inv  = rsqrtf(var + 1e-5f);
#pragma unroll
    for (int j = 0; j < 6; ++j) {
        const int h = ln + 64 * j;
        float y = (v[j] - mean) * inv * g[h] + be[h];
        y = fmaxf(y, 0.f);
        const _Float16 a = (_Float16)y;
        const size_t o = (size_t)row * HHD + h;
        o1[o] = a;
        o2[o] = (_Float16)((y - (float)a) * 2048.0f);
    }
}

// ---------------------------------------------------------------------------
// ln_proj: LayerNorm + ReLU + dot(Wl) + bl + ReLU -> z[row]. [R3]
__global__ void ln_proj_kernel(const float* __restrict__ hraw,
                               const float* __restrict__ g,
                               const float* __restrict__ be,
                               const float* __restrict__ Wl,
                               const float* __restrict__ blp,
                               float* __restrict__ zb) {
    const int row = blockIdx.x * 4 + (threadIdx.x >> 6);
    const int ln  = threadIdx.x & 63;
    const float* src = hraw + (size_t)row * HHD;
    float v[6], s = 0.f, ss = 0.f;
#pragma unroll
    for (int j = 0; j < 6; ++j) { v[j] = src[ln + 64 * j]; s += v[j]; ss += v[j] * v[j]; }
#pragma unroll
    for (int m = 32; m >= 1; m >>= 1) { s += __shfl_xor(s, m, 64); ss += __shfl_xor(ss, m, 64); }
    const float mean = s * (1.f / HHD);
    const float inv  = rsqrtf(ss * (1.f / HHD) - mean * mean + 1e-5f);
    float zs = 0.f;
#pragma unroll
    for (int j = 0; j < 6; ++j) {
        const int h = ln + 64 * j;
        float y = (v[j] - mean) * inv * g[h] + be[h];
        zs += fmaxf(y, 0.f) * Wl[h];
    }
#pragma unroll
    for (int m = 32; m >= 1; m >>= 1) zs += __shfl_xor(zs, m, 64);
    if (ln == 0) zb[row] = fmaxf(zs + blp[0], 0.f);
}

// ---------------------------------------------------------------------------
// dur_scan: durations + per-batch inclusive scan. [R3]
__global__ void dur_scan_kernel(const float* __restrict__ z,
                                float* __restrict__ durOut,
                                int* __restrict__ cum) {
    __shared__ int sb[TTOT];
    const int b = blockIdx.x;
    const int t = threadIdx.x;
    const int d = (int)floorf(expf(z[b * TTOT + t]));
    durOut[b * TTOT + t] = (float)d;
    sb[t] = d;
    __syncthreads();
    for (int off = 1; off < TTOT; off <<= 1) {
        const int v = (t >= off) ? sb[t - off] : 0;
        __syncthreads();
        sb[t] += v;
        __syncthreads();
    }
    cum[b * TTOT + t] = sb[t];
}

// ---------------------------------------------------------------------------
// gather: searchsorted + masked gather. [R3]
__global__ void gather_kernel(const float* __restrict__ X,
                              const int* __restrict__ cum,
                              float* __restrict__ aligned) {
    __shared__ int cs[TTOT];
    const int b   = blockIdx.y;
    const int tid = threadIdx.x;
    for (int e = tid; e < TTOT; e += 256) cs[e] = cum[b * TTOT + e];
    __syncthreads();
    const int pos   = blockIdx.x * 256 + tid;
    const int total = cs[TTOT - 1];
    int lo = 0, hi = TTOT;
    while (lo < hi) {
        const int mid = (lo + hi) >> 1;
        if (cs[mid] <= pos) lo = mid + 1; else hi = mid;
    }
    const float vmul = (pos < total) ? 1.f : 0.f;
    const int idx = min(lo, TTOT - 1);
    const float* Xb = X + (size_t)b * HHD * TTOT;
    float* Ab = aligned + (size_t)b * HHD * MAXL;
#pragma unroll 4
    for (int h = 0; h < HHD; ++h)
        Ab[(size_t)h * MAXL + pos] = Xb[(size_t)h * TTOT + idx] * vmul;
}

// ---------------------------------------------------------------------------
extern "C" void kernel_launch(void* const* d_in, const int* in_sizes, int n_in,
                              void* d_out, int out_size, void* d_ws, size_t ws_size,
                              hipStream_t stream) {
    const float* x   = (const float*)d_in[0];
    const float* W1  = (const float*)d_in[1];
    const float* b1  = (const float*)d_in[2];
    const float* g1  = (const float*)d_in[3];
    const float* be1 = (const float*)d_in[4];
    const float* W2  = (const float*)d_in[5];
    const float* b2  = (const float*)d_in[6];
    const float* g2  = (const float*)d_in[7];
    const float* be2 = (const float*)d_in[8];
    const float* Wl  = (const float*)d_in[9];
    const float* bl  = (const float*)d_in[10];

    float* out     = (float*)d_out;
    float* durOut  = out;                        // [B*T]
    float* aligned = out + (size_t)BB * TTOT;    // [B*H*MAXL]
    float* h_raw   = aligned;                    // alias; gather runs last

    char* ws = (char*)d_ws;
    const size_t wqB = (size_t)442368 * sizeof(_Float16);
    const size_t xtB = (size_t)BB * TTOT * HHD * sizeof(_Float16);
    _Float16* Wq1h = (_Float16*)(ws);
    _Float16* Wq1l = (_Float16*)(ws + wqB);
    _Float16* Wq2h = (_Float16*)(ws + 2 * wqB);
    _Float16* Wq2l = (_Float16*)(ws + 3 * wqB);
    _Float16* Xt1  = (_Float16*)(ws + 4 * wqB);          // reused as H1t1
    _Float16* Xt2  = (_Float16*)(ws + 4 * wqB + xtB);    // reused as H1t2
    float*    zb   = (float*)   (ws + 4 * wqB + 2 * xtB);
    int*      cum  = (int*)     (ws + 4 * wqB + 2 * xtB + (size_t)BB * TTOT * 4);

    prep_w_kernel<<<dim3(1728, 2), 256, 0, stream>>>(W1, W2, Wq1h, Wq1l, Wq2h, Wq2l);
    prep_x_kernel<<<dim3(6, 16, 32), 256, 0, stream>>>(x, Xt1, Xt2);
    conv_mfma_kernel<<<dim3(4, 8, 32), 256, 0, stream>>>(Xt1, Xt2, Wq1h, Wq1l, b1, h_raw);
    ln_split_kernel<<<8192, 256, 0, stream>>>(h_raw, g1, be1, Xt1, Xt2);
    conv_mfma_kernel<<<dim3(4, 8, 32), 256, 0, stream>>>(Xt1, Xt2, Wq2h, Wq2l, b2, h_raw);
    ln_proj_kernel<<<8192, 256, 0, stream>>>(h_raw, g2, be2, Wl, bl, zb);
    dur_scan_kernel<<<BB, TTOT, 0, stream>>>(zb, durOut, cum);
    gather_kernel<<<dim3(MAXL / 256, BB), 256, 0, stream>>>(x, cum, aligned);
}